// Round 16
// baseline (219.367 us; speedup 1.0000x reference)
//
#include <hip/hip_runtime.h>
#include <math.h>
#include <utility>

// B=16, T=16, FDIM=64, ODIM=8, NQ=10, NA=4, LAYERS=2, DEGREE=3.
// ROUND 16: TWO COLUMNS PER WAVE (ILP doubling) on the round-15 stack.
// Rationale: 15 rounds show ~58% per-wave stall invariant to gate-body,
// occupancy, code size, sync. Theory: per-gate latency (LDS coeff read +
// DPP/shuffle hazards) with one dependency cluster per gate. Two
// INDEPENDENT column streams per wave let the scheduler hide stream A's
// latency under stream B's VALU. Round 13's 4-column attempt spilled
// (128-VGPR state); 2 columns = 64-VGPR state + ~40 temps < 256 cap.
// Geometry: grid 32 x 256 thr (4 waves), 2 blocks per b (sub<2), wave w
// owns columns aa = sub*8 + w*2 + {0,1}; full column per stream
// (n = lane*16 + r), zero intra-column exchanges.
// Proven stack kept: XCD-local remap (blk = sub*16 + b), 8-party padded
// group barrier, fully-unrolled remote gather (1 remote), per-gate LDS sc
// at constexpr offsets, coefficient-masked crx, fast transcendentals,
// rank-1 pcphase mixes, Mend deleted (unitary on ancilla).

typedef float v2f __attribute__((ext_vector_type(2)));

struct Gate { int ry; int tbit; int cbit; int pidx; };
struct GateTab { Gate g[40]; };

constexpr GateTab make_gates1() {
  GateTab tb{};
  int pos = 0, idx = 0;
  for (int i = 0; i < 10; ++i) { tb.g[pos] = Gate{1, 9 - i, -1, idx}; ++pos; ++idx; }
  for (int i = 9; i >= 0; --i) { tb.g[pos] = Gate{0, 9 - ((i + 1) % 10), 9 - i, idx}; ++pos; ++idx; }
  for (int i = 0; i < 10; ++i) { tb.g[pos] = Gate{1, 9 - i, -1, idx}; ++pos; ++idx; }
  for (int k = 0; k < 10; ++k) {
    int i = (k == 0) ? 9 : (k - 1);
    tb.g[pos] = Gate{0, 9 - ((i + 9) % 10), 9 - i, idx}; ++pos; ++idx;
  }
  return tb;
}
constexpr GateTab GTC = make_gates1();

__device__ __forceinline__ int insert_zero(int v, int p) {
  return ((v >> p) << (p + 1)) | (v & ((1 << p) - 1));
}
__device__ __forceinline__ float2 cmul(float2 A, float2 B) {
  return make_float2(A.x * B.x - A.y * B.y, A.x * B.y + A.y * B.x);
}
__device__ __forceinline__ float2 conj2(float2 A) { return make_float2(A.x, -A.y); }
__device__ __forceinline__ v2f vmk(float x, float y) { v2f r; r.x = x; r.y = y; return r; }

// ---------------- cross-lane xor (DPP / ds_swizzle / permlane) ----------------
template<int XM>
__device__ __forceinline__ float lxor(float v) {
  if constexpr (XM == 1) {
    int r = __builtin_amdgcn_update_dpp(__float_as_int(v), __float_as_int(v),
                                        0xB1, 0xF, 0xF, true);
    return __int_as_float(r);
  } else if constexpr (XM == 2) {
    int r = __builtin_amdgcn_update_dpp(__float_as_int(v), __float_as_int(v),
                                        0x4E, 0xF, 0xF, true);
    return __int_as_float(r);
  } else if constexpr (XM == 4) {
    int r = __builtin_amdgcn_ds_swizzle(__float_as_int(v), 0x101F);  // xor4
    return __int_as_float(r);
  } else if constexpr (XM == 8) {
    int r = __builtin_amdgcn_update_dpp(__float_as_int(v), __float_as_int(v),
                                        0x128, 0xF, 0xF, true);      // row_ror:8
    return __int_as_float(r);
  } else if constexpr (XM == 16) {
#if __has_builtin(__builtin_amdgcn_permlane16_swap)
    unsigned uv = __float_as_uint(v);
    auto r = __builtin_amdgcn_permlane16_swap(uv, uv, false, false);
    return __uint_as_float(r[0] ^ r[1] ^ uv);
#else
    return __shfl_xor(v, 16, 64);
#endif
  } else {
#if __has_builtin(__builtin_amdgcn_permlane32_swap)
    unsigned uv = __float_as_uint(v);
    auto r = __builtin_amdgcn_permlane32_swap(uv, uv, false, false);
    return __uint_as_float(r[0] ^ r[1] ^ uv);
#else
    return __shfl_xor(v, 32, 64);
#endif
  }
}
template<int XM>
__device__ __forceinline__ v2f lxor2(v2f v) {
  v2f r; r.x = lxor<XM>(v.x); r.y = lxor<XM>(v.y); return r;
}

__device__ __forceinline__ float wave_sum(float v) {
  v += lxor<1>(v);
  v += lxor<2>(v);
  v += lxor<4>(v);
  v += lxor<8>(v);
  v += lxor<16>(v);
  v += lxor<32>(v);
  return v;
}

// ---------------- per-b group barrier (8 wave-parties, XCD-local) ----------
struct alignas(256) GBar {
  unsigned cnt;        // barrier wave-arrivals, monotonic
  unsigned gen;        // completed rounds, monotonic
  unsigned done;       // block completions, monotonic
  unsigned pad[61];
};
__device__ GBar g_gb[16];

__device__ __forceinline__ void group_barrier8(int b, int lane) {
  unsigned snap = __hip_atomic_load(&g_gb[b].gen, __ATOMIC_RELAXED, __HIP_MEMORY_SCOPE_AGENT);
  if (lane == 0) {
    unsigned old = __hip_atomic_fetch_add(&g_gb[b].cnt, 1u, __ATOMIC_ACQ_REL,
                                          __HIP_MEMORY_SCOPE_AGENT);
    if ((old & 7u) == 7u)
      __hip_atomic_store(&g_gb[b].gen, snap + 1u, __ATOMIC_RELEASE,
                         __HIP_MEMORY_SCOPE_AGENT);
  }
  while (__hip_atomic_load(&g_gb[b].gen, __ATOMIC_RELAXED, __HIP_MEMORY_SCOPE_AGENT) == snap)
    __builtin_amdgcn_s_sleep(1);
  (void)__hip_atomic_load(&g_gb[b].gen, __ATOMIC_ACQUIRE, __HIP_MEMORY_SCOPE_AGENT);
}

// ---------------- 2-column register/shuffle gate engine ----------------
template<int P>
__device__ __forceinline__ void ry_gate(v2f (&a)[2][16], const float (&c)[2],
                                        const float (&s)[2], int lane) {
  if constexpr (P < 4) {
    constexpr int m = 1 << P;
#pragma unroll
    for (int q = 0; q < 2; ++q) {
      float cc = c[q], ss = s[q];
#pragma unroll
      for (int r0 = 0; r0 < 16; ++r0) {
        if (!(r0 & m)) {
          int r1 = r0 | m;
          v2f a0 = a[q][r0], a1 = a[q][r1];
          a[q][r0] = cc * a0 - ss * a1;
          a[q][r1] = ss * a0 + cc * a1;
        }
      }
    }
  } else {
    constexpr int xm = 1 << (P - 4);
    bool up = (lane >> (P - 4)) & 1;
#pragma unroll
    for (int q = 0; q < 2; ++q) {
      float cc = c[q];
      float sg = up ? s[q] : -s[q];
#pragma unroll
      for (int r = 0; r < 16; ++r) {
        v2f wv = lxor2<xm>(a[q][r]);
        a[q][r] = cc * a[q][r] + sg * wv;
      }
    }
  }
}

// Unconditional crx rotation: v' = c v + (-i s) w
__device__ __forceinline__ v2f crot(v2f v, float c, float s, v2f w) {
  return c * v + s * vmk(w.y, -w.x);
}
template<int P>
__device__ __forceinline__ void crx_body(v2f (&a)[2][16], const float (&c)[2],
                                         const float (&s)[2], int lane) {
  if constexpr (P < 4) {
    constexpr int m = 1 << P;
#pragma unroll
    for (int q = 0; q < 2; ++q) {
      float cc = c[q], ss = s[q];
#pragma unroll
      for (int r0 = 0; r0 < 16; ++r0) {
        if (!(r0 & m)) {
          int r1 = r0 | m;
          v2f a0 = a[q][r0], a1 = a[q][r1];
          a[q][r0] = crot(a0, cc, ss, a1);
          a[q][r1] = crot(a1, cc, ss, a0);
        }
      }
    }
  } else {
    constexpr int xm = 1 << (P - 4);
#pragma unroll
    for (int q = 0; q < 2; ++q) {
      float cc = c[q], ss = s[q];
#pragma unroll
      for (int r = 0; r < 16; ++r) {
        v2f wv = lxor2<xm>(a[q][r]);
        a[q][r] = crot(a[q][r], cc, ss, wv);
      }
    }
  }
}

template<int P, int Q>
__device__ __forceinline__ void crx_gate(v2f (&a)[2][16], const float (&c)[2],
                                         const float (&s)[2], int lane) {
  if constexpr (Q >= 4) {
    // LANE-BIT control: fold predicate into coefficients ONCE per column.
    bool act = (lane >> (Q - 4)) & 1;
    float cm[2] = { act ? c[0] : 1.f, act ? c[1] : 1.f };
    float sm[2] = { act ? s[0] : 0.f, act ? s[1] : 0.f };
    crx_body<P>(a, cm, sm, lane);
  } else {
    // r-bit control: compile-time static skip (free)
    if constexpr (P < 4) {
      constexpr int m = 1 << P;
#pragma unroll
      for (int q = 0; q < 2; ++q) {
        float cc = c[q], ss = s[q];
#pragma unroll
        for (int r0 = 0; r0 < 16; ++r0) {
          if (!(r0 & m) && ((r0 >> Q) & 1)) {
            int r1 = r0 | m;
            v2f a0 = a[q][r0], a1 = a[q][r1];
            a[q][r0] = crot(a0, cc, ss, a1);
            a[q][r1] = crot(a1, cc, ss, a0);
          }
        }
      }
    } else {
      constexpr int xm = 1 << (P - 4);
#pragma unroll
      for (int q = 0; q < 2; ++q) {
        float cc = c[q], ss = s[q];
#pragma unroll
        for (int r = 0; r < 16; ++r) {
          if ((r >> Q) & 1) {
            v2f wv = lxor2<xm>(a[q][r]);
            a[q][r] = crot(a[q][r], cc, ss, wv);
          }
        }
      }
    }
  }
}

// CS: 80 for per-column ts coeffs, 0 for shared qff coeffs.
template<bool ADJ, int CS, int G>
__device__ __forceinline__ void one_gate(v2f (&a)[2][16], const float2* sc, int lane) {
  constexpr Gate g = GTC.g[ADJ ? (39 - G) : G];
  float c[2], s[2];
#pragma unroll
  for (int q = 0; q < 2; ++q) {
    float2 scv = sc[q * CS + g.pidx];     // constexpr offset
    s[q] = ADJ ? -scv.x : scv.x;
    c[q] = scv.y;
  }
  if constexpr (g.ry != 0) ry_gate<g.tbit>(a, c, s, lane);
  else crx_gate<g.tbit, g.cbit>(a, c, s, lane);
}

template<bool ADJ, int CS, int... I>
__device__ __forceinline__ void run_layer_impl(v2f (&a)[2][16], const float2* sc,
                                               int lane, std::integer_sequence<int, I...>) {
  (one_gate<ADJ, CS, I>(a, sc, lane), ...);
}
template<bool ADJ, int CS>
__device__ __forceinline__ void run_layer(v2f (&a)[2][16], const float2* sc, int lane) {
  run_layer_impl<ADJ, CS>(a, sc, lane, std::make_integer_sequence<int, 40>{});
}

// ---------------- the fused kernel ----------------
__global__ __launch_bounds__(256, 1) void k_fused(const float* __restrict__ x,
                                                  const float* __restrict__ W_fp,
                                                  const float* __restrict__ b_fp,
                                                  const float* __restrict__ prep,
                                                  const float* __restrict__ sig,
                                                  const float* __restrict__ qff,
                                                  const float* __restrict__ W_out,
                                                  const float* __restrict__ b_out,
                                                  float* __restrict__ out,
                                                  float4* __restrict__ part1,
                                                  float4* __restrict__ part2,
                                                  float* __restrict__ sv) {
  int blk = blockIdx.x;
  // XCD-local remap: blk = sub*16 + b (sub<2) -> both subs of b share blk%8
  int b = blk & 15, sub = blk >> 4;
  int tid = threadIdx.x;
  int w = tid >> 6, lane = tid & 63;
  int aa0 = sub * 8 + w * 2;          // this wave's two ancilla columns
  int aa1 = aa0 + 1;

  __shared__ __align__(16) float h[8][64];   // feature rows (t = col)
  __shared__ float2 scs[8][80];              // per-column ts (sin,cos)
  __shared__ float2 qscs[40];
  __shared__ float2 ps[32];                  // prep (sin,cos of th/2)
  __shared__ float2 es[4];                   // e^{i sig_k} = (cos, sin)
  __shared__ float2 u0s[16];                 // u0 = (prepare)|0>_anc
  __shared__ float4 R[2][512];               // 16 KB 2-slot reduction buffer

  // sv zero (ordered before atomics via barrier release chain)
  if (sub == 0 && w == 0 && lane < 30) sv[b * 30 + lane] = 0.f;

  // ---- phase 0a: h rows for this wave's 2 columns; stage small tables ----
#pragma unroll
  for (int q = 0; q < 2; ++q) {
    int cc = aa0 + q;
    int f = lane, k = f >> 1;
    float div = __expf(-(float)(2 * k) * (logf(10000.f) / 64.f));
    float ang = (float)cc * div;
    float sa, ca;
    __sincosf(ang, &sa, &ca);
    float pe = (f & 1) ? ca : sa;
    h[w * 2 + q][f] = x[(b * 64 + f) * 16 + cc] + pe;
  }
  if (w == 1) {
    if (lane < 32) {
      float s, cc;
      __sincosf(0.5f * prep[lane], &s, &cc);
      ps[lane] = make_float2(s, cc);
    } else if (lane < 36) {
      float s, cc;
      __sincosf(sig[lane - 32], &s, &cc);
      es[lane - 32] = make_float2(cc, s);
    }
  } else if (w == 2 && lane < 40) {
    float s, cc;
    __sincosf(0.5f * qff[lane], &s, &cc);
    qscs[lane] = make_float2(s, cc);
  }
  __syncthreads();

  // ---- phase 0b: wave 0 builds u0 = (prepare)|0>_anc ----
  if (w == 0) {
    float2 v[16];
#pragma unroll
    for (int i = 0; i < 16; ++i) v[i] = make_float2(i == 0 ? 1.f : 0.f, 0.f);
#pragma unroll 1
    for (int ly = 0; ly < 4; ++ly) {
#pragma unroll
      for (int qi = 0; qi < 4; ++qi) {
        int p = 3 - qi;
        float2 rc = ps[ly * 8 + qi * 2 + 0];      // ry
        {
          float s = rc.x, cc = rc.y;
#pragma unroll
          for (int m = 0; m < 8; ++m) {
            int a0 = insert_zero(m, p), a1 = a0 | (1 << p);
            float2 t0 = v[a0], t1 = v[a1];
            v[a0] = make_float2(cc * t0.x - s * t1.x, cc * t0.y - s * t1.y);
            v[a1] = make_float2(s * t0.x + cc * t1.x, s * t0.y + cc * t1.y);
          }
        }
        rc = ps[ly * 8 + qi * 2 + 1];             // rz
        {
          float s = rc.x, cc = rc.y;
#pragma unroll
          for (int m = 0; m < 8; ++m) {
            int a0 = insert_zero(m, p), a1 = a0 | (1 << p);
            float2 t0 = v[a0], t1 = v[a1];
            v[a0] = make_float2(cc * t0.x + s * t0.y, cc * t0.y - s * t0.x);
            v[a1] = make_float2(cc * t1.x - s * t1.y, cc * t1.y + s * t1.x);
          }
        }
      }
#pragma unroll
      for (int i = 0; i < 3; ++i) {
        int pc = 3 - i, pt = 2 - i;
#pragma unroll
        for (int m = 0; m < 4; ++m) {
          int mm = insert_zero(m, pt);
          mm = insert_zero(mm, pc);
          int a0 = mm | (1 << pc), a1 = a0 | (1 << pt);
          float2 t0 = v[a0], t1 = v[a1];
          v[a0] = t1; v[a1] = t0;
        }
      }
    }
    if (lane == 0) {
#pragma unroll
      for (int i = 0; i < 16; ++i) u0s[i] = v[i];
    }
  }

  // ---- phase 0c: ts dot products for this wave's 2 columns ----
#pragma unroll 1
  for (int q = 0; q < 2; ++q) {
    int cc = w * 2 + q;
    const float4* h4 = (const float4*)&h[cc][0];
    for (int j = lane; j < 80; j += 64) {
      float acc = b_fp[j];
      const float4* w4 = (const float4*)(W_fp + j * 64);
#pragma unroll
      for (int k4 = 0; k4 < 16; ++k4) {
        float4 hh = h4[k4], ww = w4[k4];
        acc += hh.x * ww.x + hh.y * ww.y + hh.z * ww.z + hh.w * ww.w;
      }
      float sg = 1.f / (1.f + __expf(-acc));
      float s, cf;
      __sincosf(sg * 3.14159265358979323846f, &s, &cf);   // theta/2 = sigmoid*pi
      scs[cc][j] = make_float2(s, cf);
    }
  }
  __syncthreads();                     // u0s + scs + es visible

  float2 e0 = es[0], e1 = es[1], e2 = es[2];
  float2 u0c[2], m0c[2];
  u0c[0] = u0s[aa0]; u0c[1] = u0s[aa1];
  m0c[0] = cmul(u0c[0], e0); m0c[1] = cmul(u0c[1], e0);
  float2 ceA = conj2(e1), ceB = conj2(e2);

  const float2* sc = &scs[w * 2][0];   // col q offset = q*80 (constexpr)
  v2f a[2][16];
#pragma unroll
  for (int q = 0; q < 2; ++q) {
#pragma unroll
    for (int r = 0; r < 16; ++r) a[q][r] = vmk(0.f, 0.f);
    if (lane == 0) a[q][0] = vmk(m0c[q].x, m0c[q].y);
  }

  // ---- 7 layer-passes; mixes before passes 2 and 4 ----
  // ph: 0 F sc | 1 F sc+40 | 2 mix1,A sc+40 | 3 A sc | 4 mix2,F sc | 5 F sc+40 | 6 F qscs
#pragma unroll 1
  for (int ph = 0; ph < 7; ++ph) {
    if (ph == 2 || ph == 4) {
      float2 ce = (ph == 2) ? ceA : ceB;
      float ey = (ph == 2) ? e1.y : e2.y;
      float4* part = (ph == 2) ? part1 : part2;

      // wave partial over its 2 columns: p[r] = sum_q conj(u0)*a[q][r]
      __syncthreads();               // R free (prev readers done)
      if (w < 2) {
#pragma unroll
        for (int qq = 0; qq < 8; ++qq) {
          float px0 = 0.f, py0 = 0.f, px1 = 0.f, py1 = 0.f;
#pragma unroll
          for (int q = 0; q < 2; ++q) {
            float2 cu = conj2(u0c[q]);
            v2f a0 = a[q][2 * qq], a1 = a[q][2 * qq + 1];
            px0 += cu.x * a0.x - cu.y * a0.y;
            py0 += cu.x * a0.y + cu.y * a0.x;
            px1 += cu.x * a1.x - cu.y * a1.y;
            py1 += cu.x * a1.y + cu.y * a1.x;
          }
          R[w][qq * 64 + lane] = make_float4(px0, py0, px1, py1);
        }
      }
      __syncthreads();
      if (w >= 2) {
#pragma unroll
        for (int qq = 0; qq < 8; ++qq) {
          float4 v = R[w - 2][qq * 64 + lane];
#pragma unroll
          for (int q = 0; q < 2; ++q) {
            float2 cu = conj2(u0c[q]);
            v2f a0 = a[q][2 * qq], a1 = a[q][2 * qq + 1];
            v.x += cu.x * a0.x - cu.y * a0.y;
            v.y += cu.x * a0.y + cu.y * a0.x;
            v.z += cu.x * a1.x - cu.y * a1.y;
            v.w += cu.x * a1.y + cu.y * a1.x;
          }
          R[w - 2][qq * 64 + lane] = v;
        }
      }
      __syncthreads();
      // block partial (R0+R1) -> global, 2 q-slices per wave, coalesced
#pragma unroll
      for (int qq = 0; qq < 2; ++qq) {
        int q = w * 2 + qq;
        float4 v0 = R[0][q * 64 + lane];
        float4 v1 = R[1][q * 64 + lane];
        part[(size_t)(b * 2 + sub) * 512 + q * 64 + lane] =
            make_float4(v0.x + v1.x, v0.y + v1.y, v0.z + v1.z, v0.w + v1.w);
      }
      group_barrier8(b, lane);       // release covers stores; acquire for reads

      // s = own block partial (LDS) + 1 remote block partial (XCD-local L2)
      float4 s4[8];
#pragma unroll
      for (int q = 0; q < 8; ++q) {
        float4 v0 = R[0][q * 64 + lane];
        float4 v1 = R[1][q * 64 + lane];
        s4[q] = make_float4(v0.x + v1.x, v0.y + v1.y, v0.z + v1.z, v0.w + v1.w);
      }
      {
        const float4* pp = part + (size_t)(b * 2 + (sub ^ 1)) * 512 + lane;
#pragma unroll
        for (int q = 0; q < 8; ++q) {
          float4 v = pp[q * 64];
          s4[q].x += v.x; s4[q].y += v.y; s4[q].z += v.z; s4[q].w += v.w;
        }
      }
      // col <- ce*col + wk(col)*s,  wk = (-2 ey u0.y, 2 ey u0.x)
#pragma unroll
      for (int q = 0; q < 2; ++q) {
        float2 wk = make_float2(-2.f * ey * u0c[q].y, 2.f * ey * u0c[q].x);
#pragma unroll
        for (int qq = 0; qq < 8; ++qq) {
          v2f a0 = a[q][2 * qq], a1 = a[q][2 * qq + 1];
          a[q][2 * qq] = vmk(ce.x * a0.x - ce.y * a0.y + wk.x * s4[qq].x - wk.y * s4[qq].y,
                             ce.x * a0.y + ce.y * a0.x + wk.x * s4[qq].y + wk.y * s4[qq].x);
          a[q][2 * qq + 1] = vmk(ce.x * a1.x - ce.y * a1.y + wk.x * s4[qq].z - wk.y * s4[qq].w,
                                 ce.x * a1.y + ce.y * a1.x + wk.x * s4[qq].w + wk.y * s4[qq].z);
        }
      }
    }
    if (ph == 2)      run_layer<true, 80>(a, sc + 40, lane);
    else if (ph == 3) run_layer<true, 80>(a, sc, lane);
    else if (ph == 6) run_layer<false, 0>(a, &qscs[0], lane);
    else              run_layer<false, 80>(a, sc + ((ph == 1 || ph == 5) ? 40 : 0), lane);
  }

  // ---- expvals: accumulate over this wave's 2 columns (obs additive) ----
  {
    float obs[30];
#pragma unroll
    for (int p = 0; p <= 9; ++p) {
      int i = 9 - p;
      float cr = 0.f, ci = 0.f, zz = 0.f;
      if (p < 4) {
        int m = 1 << p;
#pragma unroll
        for (int q = 0; q < 2; ++q) {
#pragma unroll
          for (int r0 = 0; r0 < 16; ++r0) {
            if (!(r0 & m)) {
              v2f A0 = a[q][r0], A1 = a[q][r0 | m];
              cr += A0.x * A1.x + A0.y * A1.y;
              ci += A0.x * A1.y - A0.y * A1.x;
              zz += (A0.x * A0.x + A0.y * A0.y) - (A1.x * A1.x + A1.y * A1.y);
            }
          }
        }
      } else {
        int xm = 1 << (p - 4);
        bool up = (lane >> (p - 4)) & 1;
#pragma unroll
        for (int q = 0; q < 2; ++q) {
#pragma unroll
          for (int r = 0; r < 16; ++r) {
            float wx = __shfl_xor(a[q][r].x, xm, 64);
            float wy = __shfl_xor(a[q][r].y, xm, 64);
            float n2 = a[q][r].x * a[q][r].x + a[q][r].y * a[q][r].y;
            if (!up) {
              cr += a[q][r].x * wx + a[q][r].y * wy;
              ci += a[q][r].x * wy - a[q][r].y * wx;
              zz += n2;
            } else {
              zz -= n2;
            }
          }
        }
      }
      obs[i] = 2.f * cr;
      obs[10 + i] = 2.f * ci;
      obs[20 + i] = zz;
    }
#pragma unroll
    for (int j = 0; j < 30; ++j) obs[j] = wave_sum(obs[j]);

    float* Rf = (float*)R;
    __syncthreads();                 // R free (mix-2 gathers done)
    if (lane == 0) {
#pragma unroll
      for (int j = 0; j < 30; ++j) Rf[w * 30 + j] = obs[j];
    }
    __syncthreads();
    if (w == 0) {
      if (lane < 30) {
        float v = Rf[0 * 30 + lane] + Rf[1 * 30 + lane] +
                  Rf[2 * 30 + lane] + Rf[3 * 30 + lane];
        atomicAdd(&sv[b * 30 + lane], v);
      }
      // last-arriving block of the pair computes the output row
      int lastflag = 0;
      if (lane == 0) {
        unsigned old = __hip_atomic_fetch_add(&g_gb[b].done, 1u, __ATOMIC_ACQ_REL,
                                              __HIP_MEMORY_SCOPE_AGENT);
        lastflag = ((old & 1u) == 1u) ? 1 : 0;
      }
      lastflag = __shfl(lastflag, 0, 64);
      if (lastflag) {
        (void)__hip_atomic_load(&g_gb[b].done, __ATOMIC_ACQUIRE, __HIP_MEMORY_SCOPE_AGENT);
        if (lane < 8) {
          float acc = b_out[lane];
#pragma unroll
          for (int j = 0; j < 30; ++j) acc += W_out[lane * 30 + j] * sv[b * 30 + j];
          out[b * 8 + lane] = acc;
        }
      }
    }
  }
}

extern "C" void kernel_launch(void* const* d_in, const int* in_sizes, int n_in,
                              void* d_out, int out_size, void* d_ws, size_t ws_size,
                              hipStream_t stream) {
  const float* x     = (const float*)d_in[0];
  const float* W_fp  = (const float*)d_in[1];
  const float* b_fp  = (const float*)d_in[2];
  const float* prep  = (const float*)d_in[3];
  const float* sig   = (const float*)d_in[4];
  const float* qff   = (const float*)d_in[5];
  const float* W_out = (const float*)d_in[6];
  const float* b_out = (const float*)d_in[7];
  float* out = (float*)d_out;
  (void)in_sizes; (void)n_in; (void)out_size;

  // ws: part1 (256 KB) | part2 (256 KB) | sv (1920 B). Needs ~515 KB.
  char* ws = (char*)d_ws;
  const size_t SZ_PART = (size_t)32 * 512 * 16;   // 32 block-partials * 8 KB
  float4* part1 = (float4*)ws;
  float4* part2 = (float4*)(ws + SZ_PART);
  float*  sv    = (float*)(ws + 2 * SZ_PART);
  (void)ws_size;

  k_fused<<<dim3(32), dim3(256), 0, stream>>>(x, W_fp, b_fp, prep, sig, qff,
                                              W_out, b_out, out, part1, part2, sv);
}

// Round 17
// 144.378 us; speedup vs baseline: 1.5194x; 1.5194x over previous
//
#include <hip/hip_runtime.h>
#include <math.h>
#include <utility>

// B=16, T=16, FDIM=64, ODIM=8, NQ=10, NA=4, LAYERS=2, DEGREE=3.
// ROUND 17 = ROUND 14 VERBATIM (best timed result of all rounds: 145.9us).
// Deliberate revert-to-best after r15/r16 structural probes regressed.
// Structure: column split across 2 waves (n = [lane5:3|wbit|lane2:0|r2:0],
// 8 v2f/thr), grid 128 x 256 thr, 1 wave/SIMD; XCD-local block remap
// (blk = sub*16 + b); sc read per-gate from LDS at constexpr offsets;
// X/R in [r][lane] layout; rank-1 pcphase mixes; Mend deleted (unitary on
// ancilla); coefficient-masked crx for lane-bit controls; fast
// transcendentals in phase 0.
// Measured machine model (16 rounds): per-gate cost ~700cyc serial per
// SIMD; 0% overlap across waves on one SIMD (r8), ~25-40% with a second
// in-wave stream (r16). 280-gate chain ~= 82us critical path; + ~41us
// harness poison fill + launch overhead = the ~146us timed floor.

typedef float v2f __attribute__((ext_vector_type(2)));

struct Gate { int ry; int tbit; int cbit; int pidx; };
struct GateTab { Gate g[40]; };

constexpr GateTab make_gates1() {
  GateTab tb{};
  int pos = 0, idx = 0;
  for (int i = 0; i < 10; ++i) { tb.g[pos] = Gate{1, 9 - i, -1, idx}; ++pos; ++idx; }
  for (int i = 9; i >= 0; --i) { tb.g[pos] = Gate{0, 9 - ((i + 1) % 10), 9 - i, idx}; ++pos; ++idx; }
  for (int i = 0; i < 10; ++i) { tb.g[pos] = Gate{1, 9 - i, -1, idx}; ++pos; ++idx; }
  for (int k = 0; k < 10; ++k) {
    int i = (k == 0) ? 9 : (k - 1);
    tb.g[pos] = Gate{0, 9 - ((i + 9) % 10), 9 - i, idx}; ++pos; ++idx;
  }
  return tb;
}
constexpr GateTab GTC = make_gates1();

constexpr int lanebit_of(int P) {       // lane-bit index for P in {3,4,5,7,8,9}
  return P == 3 ? 0 : P == 4 ? 1 : P == 5 ? 2 : P == 7 ? 3 : P == 8 ? 4 : 5;
}

__device__ __forceinline__ int insert_zero(int v, int p) {
  return ((v >> p) << (p + 1)) | (v & ((1 << p) - 1));
}
__device__ __forceinline__ float2 cmul(float2 A, float2 B) {
  return make_float2(A.x * B.x - A.y * B.y, A.x * B.y + A.y * B.x);
}
__device__ __forceinline__ float2 conj2(float2 A) { return make_float2(A.x, -A.y); }
__device__ __forceinline__ v2f vmk(float x, float y) { v2f r; r.x = x; r.y = y; return r; }

// ---------------- cross-lane xor (DPP / ds_swizzle / permlane) ----------------
template<int XM>
__device__ __forceinline__ float lxor(float v) {
  if constexpr (XM == 1) {
    int r = __builtin_amdgcn_update_dpp(__float_as_int(v), __float_as_int(v),
                                        0xB1, 0xF, 0xF, true);
    return __int_as_float(r);
  } else if constexpr (XM == 2) {
    int r = __builtin_amdgcn_update_dpp(__float_as_int(v), __float_as_int(v),
                                        0x4E, 0xF, 0xF, true);
    return __int_as_float(r);
  } else if constexpr (XM == 4) {
    int r = __builtin_amdgcn_ds_swizzle(__float_as_int(v), 0x101F);  // xor4
    return __int_as_float(r);
  } else if constexpr (XM == 8) {
    int r = __builtin_amdgcn_update_dpp(__float_as_int(v), __float_as_int(v),
                                        0x128, 0xF, 0xF, true);      // row_ror:8
    return __int_as_float(r);
  } else if constexpr (XM == 16) {
#if __has_builtin(__builtin_amdgcn_permlane16_swap)
    unsigned uv = __float_as_uint(v);
    auto r = __builtin_amdgcn_permlane16_swap(uv, uv, false, false);
    return __uint_as_float(r[0] ^ r[1] ^ uv);
#else
    return __shfl_xor(v, 16, 64);
#endif
  } else {
#if __has_builtin(__builtin_amdgcn_permlane32_swap)
    unsigned uv = __float_as_uint(v);
    auto r = __builtin_amdgcn_permlane32_swap(uv, uv, false, false);
    return __uint_as_float(r[0] ^ r[1] ^ uv);
#else
    return __shfl_xor(v, 32, 64);
#endif
  }
}
template<int XM>
__device__ __forceinline__ v2f lxor2(v2f v) {
  v2f r; r.x = lxor<XM>(v.x); r.y = lxor<XM>(v.y); return r;
}

__device__ __forceinline__ float wave_sum(float v) {
  v += lxor<1>(v);
  v += lxor<2>(v);
  v += lxor<4>(v);
  v += lxor<8>(v);
  v += lxor<16>(v);
  v += lxor<32>(v);
  return v;
}

// ---------------- per-b group barrier (32 wave-parties, XCD-local) ----------
struct alignas(256) GBar {
  unsigned cnt;        // barrier wave-arrivals, monotonic
  unsigned gen;        // completed rounds, monotonic
  unsigned done;       // block completions, monotonic
  unsigned pad[61];
};
__device__ GBar g_gb[16];

__device__ __forceinline__ void group_barrier32(int b, int lane) {
  unsigned snap = __hip_atomic_load(&g_gb[b].gen, __ATOMIC_RELAXED, __HIP_MEMORY_SCOPE_AGENT);
  if (lane == 0) {
    unsigned old = __hip_atomic_fetch_add(&g_gb[b].cnt, 1u, __ATOMIC_ACQ_REL,
                                          __HIP_MEMORY_SCOPE_AGENT);
    if ((old & 31u) == 31u)
      __hip_atomic_store(&g_gb[b].gen, snap + 1u, __ATOMIC_RELEASE,
                         __HIP_MEMORY_SCOPE_AGENT);
  }
  while (__hip_atomic_load(&g_gb[b].gen, __ATOMIC_RELAXED, __HIP_MEMORY_SCOPE_AGENT) == snap)
    __builtin_amdgcn_s_sleep(1);
  (void)__hip_atomic_load(&g_gb[b].gen, __ATOMIC_ACQUIRE, __HIP_MEMORY_SCOPE_AGENT);
}

// ---------------- gate engine context (wave-split exchange) ----------------
// X layout: [c][buf][wbit][r][lane] -> per-lane stride 8B (2-way bank, free)
struct Ctx {
  int lane, wbit;
  int buf;                       // double-buffer parity for exchanges
  float2* xo0; float2* xo1;      // own slots (buf 0/1), element stride 64
  const float2* xp0; const float2* xp1;  // partner slots
};

// Exchange: write own 8 regs, one barrier, return partner pointer; toggle buf.
__device__ __forceinline__ const float2* xchg(v2f (&a)[8], Ctx& ctx) {
  float2* wo = ctx.buf ? ctx.xo1 : ctx.xo0;
#pragma unroll
  for (int r = 0; r < 8; ++r) wo[r * 64] = make_float2(a[r].x, a[r].y);
  __syncthreads();
  const float2* wp = ctx.buf ? ctx.xp1 : ctx.xp0;
  ctx.buf ^= 1;
  return wp;
}

template<int P>
__device__ __forceinline__ void ry_gate(v2f (&a)[8], float c, float s, Ctx& ctx) {
  if constexpr (P < 3) {
    constexpr int m = 1 << P;
#pragma unroll
    for (int r0 = 0; r0 < 8; ++r0) {
      if (!(r0 & m)) {
        int r1 = r0 | m;
        v2f a0 = a[r0], a1 = a[r1];
        a[r0] = c * a0 - s * a1;
        a[r1] = s * a0 + c * a1;
      }
    }
  } else if constexpr (P == 6) {
    const float2* wp = xchg(a, ctx);
    float sg = ctx.wbit ? s : -s;
#pragma unroll
    for (int r = 0; r < 8; ++r) {
      float2 w = wp[r * 64];
      a[r] = c * a[r] + sg * vmk(w.x, w.y);
    }
  } else {
    constexpr int xm = 1 << lanebit_of(P);
    bool up = (ctx.lane >> lanebit_of(P)) & 1;
    float sg = up ? s : -s;
#pragma unroll
    for (int r = 0; r < 8; ++r) {
      v2f wv = lxor2<xm>(a[r]);
      a[r] = c * a[r] + sg * wv;
    }
  }
}

// Unconditional crx rotation body on target P (incl. P==6 exchange).
__device__ __forceinline__ v2f crot(v2f v, float c, float s, v2f w) {
  return c * v + s * vmk(w.y, -w.x);   // v' = c v + (-i s) w
}
template<int P>
__device__ __forceinline__ void crx_body(v2f (&a)[8], float c, float s, Ctx& ctx) {
  if constexpr (P == 6) {
    const float2* wp = xchg(a, ctx);
#pragma unroll
    for (int r = 0; r < 8; ++r) {
      float2 w = wp[r * 64];
      a[r] = crot(a[r], c, s, vmk(w.x, w.y));
    }
  } else if constexpr (P < 3) {
    constexpr int m = 1 << P;
#pragma unroll
    for (int r0 = 0; r0 < 8; ++r0) {
      if (!(r0 & m)) {
        int r1 = r0 | m;
        v2f a0 = a[r0], a1 = a[r1];
        a[r0] = crot(a0, c, s, a1);
        a[r1] = crot(a1, c, s, a0);
      }
    }
  } else {
    constexpr int xm = 1 << lanebit_of(P);
#pragma unroll
    for (int r = 0; r < 8; ++r) {
      v2f wv = lxor2<xm>(a[r]);
      a[r] = crot(a[r], c, s, wv);
    }
  }
}

template<int P, int Q>
__device__ __forceinline__ void crx_gate(v2f (&a)[8], float c, float s, Ctx& ctx) {
  if constexpr (Q == 6) {
    // wave-uniform control (P != 6 always; no syncs inside body)
    if (ctx.wbit) crx_body<P>(a, c, s, ctx);
  } else if constexpr (Q >= 3) {
    // LANE-BIT control: fold predicate into coefficients ONCE (2 cndmask)
    // instead of per-register cndmask pairs. Inactive: 1*a + 0*w = a exactly.
    constexpr int lb = lanebit_of(Q);
    bool act = (ctx.lane >> lb) & 1;
    float cm = act ? c : 1.f;
    float sm = act ? s : 0.f;
    crx_body<P>(a, cm, sm, ctx);
  } else {
    // r-bit control: compile-time static skip (free)
    if constexpr (P == 6) {
      const float2* wp = xchg(a, ctx);
#pragma unroll
      for (int r = 0; r < 8; ++r) {
        if ((r >> Q) & 1) {
          float2 w = wp[r * 64];
          a[r] = crot(a[r], c, s, vmk(w.x, w.y));
        }
      }
    } else if constexpr (P < 3) {
      constexpr int m = 1 << P;
#pragma unroll
      for (int r0 = 0; r0 < 8; ++r0) {
        if (!(r0 & m) && ((r0 >> Q) & 1)) {
          int r1 = r0 | m;
          v2f a0 = a[r0], a1 = a[r1];
          a[r0] = crot(a0, c, s, a1);
          a[r1] = crot(a1, c, s, a0);
        }
      }
    } else {
      constexpr int xm = 1 << lanebit_of(P);
#pragma unroll
      for (int r = 0; r < 8; ++r) {
        if ((r >> Q) & 1) {
          v2f wv = lxor2<xm>(a[r]);
          a[r] = crot(a[r], c, s, wv);
        }
      }
    }
  }
}

// Direct LDS read of the gate's (sin,cos): constexpr offset from sc base.
template<bool ADJ, int G>
__device__ __forceinline__ void one_gate(v2f (&a)[8], const float2* sc, Ctx& ctx) {
  constexpr Gate g = GTC.g[ADJ ? (39 - G) : G];
  float2 scv = sc[g.pidx];
  float s = ADJ ? -scv.x : scv.x;
  float c = scv.y;
  if constexpr (g.ry != 0) ry_gate<g.tbit>(a, c, s, ctx);
  else crx_gate<g.tbit, g.cbit>(a, c, s, ctx);
}

template<bool ADJ, int... I>
__device__ __forceinline__ void run_layer_impl(v2f (&a)[8], const float2* sc,
                                               Ctx& ctx, std::integer_sequence<int, I...>) {
  (one_gate<ADJ, I>(a, sc, ctx), ...);
}

template<bool ADJ>
__device__ __forceinline__ void run_layer(v2f (&a)[8], const float2* sc, Ctx& ctx) {
  run_layer_impl<ADJ>(a, sc, ctx, std::make_integer_sequence<int, 40>{});
}

// ---------------- the fused kernel ----------------
__global__ __launch_bounds__(256, 1) void k_fused(const float* __restrict__ x,
                                                  const float* __restrict__ W_fp,
                                                  const float* __restrict__ b_fp,
                                                  const float* __restrict__ prep,
                                                  const float* __restrict__ sig,
                                                  const float* __restrict__ qff,
                                                  const float* __restrict__ W_out,
                                                  const float* __restrict__ b_out,
                                                  float* __restrict__ out,
                                                  float4* __restrict__ part1,
                                                  float4* __restrict__ part2,
                                                  float* __restrict__ sv) {
  int blk = blockIdx.x;
  // XCD-local remap: blk = sub*16 + b  ->  all 8 subs of b share blk%8 = b%8
  int b = blk & 15, sub = blk >> 4;
  int tid = threadIdx.x;
  int w = tid >> 6, lane = tid & 63;
  int c = w >> 1, wbit = w & 1;
  int aa = sub * 2 + c;               // this column's ancilla index

  __shared__ float2 X[2][2][2][8][64];       // [c][buf][wbit][r][lane] 16 KB
  __shared__ __align__(16) float2 R2[1024];  // 8 KB partial [wbit][r][lane]
  __shared__ __align__(16) float h[2][64];
  __shared__ float2 scs[2][80];
  __shared__ float2 qscs[40];
  __shared__ float2 ps[32];
  __shared__ float2 es[4];
  __shared__ float2 u0s[16];

  // sv zero (ordered before final atomics via barrier release chain)
  if (sub == 0 && w == 0 && lane < 30) sv[b * 30 + lane] = 0.f;

  // ---- phase 0a: h rows + small tables (fast transcendentals) ----
  if (wbit == 0) {
    int f = lane, k = f >> 1;
    float div = __expf(-(float)(2 * k) * (logf(10000.f) / 64.f));
    float ang = (float)aa * div;
    float sa, ca;
    __sincosf(ang, &sa, &ca);
    float pe = (f & 1) ? ca : sa;
    h[c][f] = x[(b * 64 + f) * 16 + aa] + pe;
  }
  if (w == 1) {
    if (lane < 32) {
      float s, cc;
      __sincosf(0.5f * prep[lane], &s, &cc);
      ps[lane] = make_float2(s, cc);
    } else if (lane < 36) {
      float s, cc;
      __sincosf(sig[lane - 32], &s, &cc);
      es[lane - 32] = make_float2(cc, s);
    }
  } else if (w == 3 && lane < 40) {
    float s, cc;
    __sincosf(0.5f * qff[lane], &s, &cc);
    qscs[lane] = make_float2(s, cc);
  }
  __syncthreads();

  // ---- phase 0b: wave 0 builds u0 = (prepare)|0>_anc ----
  if (w == 0) {
    float2 v[16];
#pragma unroll
    for (int i = 0; i < 16; ++i) v[i] = make_float2(i == 0 ? 1.f : 0.f, 0.f);
#pragma unroll 1
    for (int ly = 0; ly < 4; ++ly) {
#pragma unroll
      for (int qi = 0; qi < 4; ++qi) {
        int p = 3 - qi;
        float2 rc = ps[ly * 8 + qi * 2 + 0];      // ry
        {
          float s = rc.x, cc = rc.y;
#pragma unroll
          for (int m = 0; m < 8; ++m) {
            int a0 = insert_zero(m, p), a1 = a0 | (1 << p);
            float2 t0 = v[a0], t1 = v[a1];
            v[a0] = make_float2(cc * t0.x - s * t1.x, cc * t0.y - s * t1.y);
            v[a1] = make_float2(s * t0.x + cc * t1.x, s * t0.y + cc * t1.y);
          }
        }
        rc = ps[ly * 8 + qi * 2 + 1];             // rz
        {
          float s = rc.x, cc = rc.y;
#pragma unroll
          for (int m = 0; m < 8; ++m) {
            int a0 = insert_zero(m, p), a1 = a0 | (1 << p);
            float2 t0 = v[a0], t1 = v[a1];
            v[a0] = make_float2(cc * t0.x + s * t0.y, cc * t0.y - s * t0.x);
            v[a1] = make_float2(cc * t1.x - s * t1.y, cc * t1.y + s * t1.x);
          }
        }
      }
#pragma unroll
      for (int i = 0; i < 3; ++i) {
        int pc = 3 - i, pt = 2 - i;
#pragma unroll
        for (int m = 0; m < 4; ++m) {
          int mm = insert_zero(m, pt);
          mm = insert_zero(mm, pc);
          int a0 = mm | (1 << pc), a1 = a0 | (1 << pt);
          float2 t0 = v[a0], t1 = v[a1];
          v[a0] = t1; v[a1] = t0;
        }
      }
    }
    if (lane == 0) {
#pragma unroll
      for (int i = 0; i < 16; ++i) u0s[i] = v[i];
    }
  }

  // ---- phase 0c: ts dot products (each wave does 40 of its column's 80) ----
  if (lane < 40) {
    int j = wbit * 40 + lane;
    const float4* h4 = (const float4*)&h[c][0];
    float acc = b_fp[j];
    const float4* w4 = (const float4*)(W_fp + j * 64);
#pragma unroll
    for (int k4 = 0; k4 < 16; ++k4) {
      float4 hh = h4[k4], ww = w4[k4];
      acc += hh.x * ww.x + hh.y * ww.y + hh.z * ww.z + hh.w * ww.w;
    }
    float sg = 1.f / (1.f + __expf(-acc));
    float s, cc;
    __sincosf(sg * 3.14159265358979323846f, &s, &cc);   // theta/2 = sigmoid*pi
    scs[c][j] = make_float2(s, cc);
  }
  __syncthreads();                     // u0s + scs + es visible

  float2 u0aa = u0s[aa];
  float2 e0 = es[0], e1 = es[1], e2 = es[2];
  float2 m0  = cmul(u0aa, e0);
  float2 cu0 = conj2(u0aa);
  float2 ceA = conj2(e1);
  float2 wA  = make_float2(-2.f * e1.y * u0aa.y, 2.f * e1.y * u0aa.x);
  float2 ceB = conj2(e2);
  float2 wB  = make_float2(-2.f * e2.y * u0aa.y, 2.f * e2.y * u0aa.x);

  Ctx ctx;
  ctx.lane = lane; ctx.wbit = wbit; ctx.buf = 0;
  ctx.xo0 = &X[c][0][wbit][0][lane];
  ctx.xo1 = &X[c][1][wbit][0][lane];
  ctx.xp0 = &X[c][0][wbit ^ 1][0][lane];
  ctx.xp1 = &X[c][1][wbit ^ 1][0][lane];

  const float2* sc = &scs[c][0];
  v2f a[8];
#pragma unroll
  for (int r = 0; r < 8; ++r) a[r] = vmk(0.f, 0.f);
  if (wbit == 0 && lane == 0) a[0] = vmk(m0.x, m0.y);   // n = 0

  // ---- 7 layer-passes; mixes before passes 2 and 4 ----
  // ph: 0 F sc | 1 F sc+40 | 2 mix1,A sc+40 | 3 A sc | 4 mix2,F sc | 5 F sc+40 | 6 F qscs
#pragma unroll 1
  for (int ph = 0; ph < 7; ++ph) {
    if (ph == 2 || ph == 4) {
      float2 ce = (ph == 2) ? ceA : ceB;
      float2 wk = (ph == 2) ? wA : wB;
      float4* part = (ph == 2) ? part1 : part2;
      int base = wbit * 512 + lane;    // [wbit][r][lane], element stride 64

      __syncthreads();               // R2 free
      if (c == 0) {
#pragma unroll
        for (int r = 0; r < 8; ++r)
          R2[base + r * 64] = cmul(cu0, make_float2(a[r].x, a[r].y));
      }
      __syncthreads();
      if (c == 1) {
#pragma unroll
        for (int r = 0; r < 8; ++r) {
          float2 v = R2[base + r * 64];
          float2 p = cmul(cu0, make_float2(a[r].x, a[r].y));
          R2[base + r * 64] = make_float2(v.x + p.x, v.y + p.y);
        }
      }
      __syncthreads();
      // block partial -> global (linear byte copy; 512 float4, 2/thread)
      {
        float4* dst = part + (size_t)(b * 8 + sub) * 512;
        const float4* src = (const float4*)R2;
        dst[tid] = src[tid];
        dst[tid + 256] = src[tid + 256];
      }
      group_barrier32(b, lane);      // release covers stores; acquire for reads

      // s = own block partial (LDS) + 7 remote block partials (XCD-local L2);
      // FULLY unrolled -> all 56 loads issued before the wait.
      float2 s2[8];
#pragma unroll
      for (int r = 0; r < 8; ++r) s2[r] = R2[base + r * 64];
#pragma unroll
      for (int o = 1; o < 8; ++o) {
        int so = (sub + o) & 7;
        const float2* pp = (const float2*)(part + (size_t)(b * 8 + so) * 512);
#pragma unroll
        for (int r = 0; r < 8; ++r) {
          float2 v = pp[base + r * 64];
          s2[r].x += v.x; s2[r].y += v.y;
        }
      }
      // col <- ce*col + wk*s
#pragma unroll
      for (int r = 0; r < 8; ++r) {
        v2f a0 = a[r];
        a[r] = vmk(ce.x * a0.x - ce.y * a0.y + wk.x * s2[r].x - wk.y * s2[r].y,
                   ce.x * a0.y + ce.y * a0.x + wk.x * s2[r].y + wk.y * s2[r].x);
      }
    }
    const float2* scp;
    if (ph == 6) scp = &qscs[0];
    else scp = sc + ((ph == 1 || ph == 2 || ph == 5) ? 40 : 0);
    if (ph == 2 || ph == 3) run_layer<true>(a, scp, ctx);
    else                    run_layer<false>(a, scp, ctx);
  }

  // ---- expvals ----
  {
    float obs[30];
#pragma unroll
    for (int p = 0; p <= 9; ++p) {
      int i = 9 - p;
      float cr = 0.f, ci = 0.f, zz = 0.f;
      if (p < 3) {
        int m = 1 << p;
#pragma unroll
        for (int r0 = 0; r0 < 8; ++r0) {
          if (!(r0 & m)) {
            v2f A0 = a[r0], A1 = a[r0 | m];
            cr += A0.x * A1.x + A0.y * A1.y;
            ci += A0.x * A1.y - A0.y * A1.x;
            zz += (A0.x * A0.x + A0.y * A0.y) - (A1.x * A1.x + A1.y * A1.y);
          }
        }
      } else if (p == 6) {
        // cross-wave observable: exchange, low half computes cr/ci
        float2* wo = ctx.buf ? ctx.xo1 : ctx.xo0;
#pragma unroll
        for (int r = 0; r < 8; ++r) wo[r * 64] = make_float2(a[r].x, a[r].y);
        __syncthreads();
        const float2* wp = ctx.buf ? ctx.xp1 : ctx.xp0;
        ctx.buf ^= 1;
#pragma unroll
        for (int r = 0; r < 8; ++r) {
          float n2 = a[r].x * a[r].x + a[r].y * a[r].y;
          if (wbit == 0) {
            float2 ww = wp[r * 64];
            cr += a[r].x * ww.x + a[r].y * ww.y;
            ci += a[r].x * ww.y - a[r].y * ww.x;
            zz += n2;
          } else {
            zz -= n2;
          }
        }
      } else {
        int lb = (p == 3) ? 0 : (p == 4) ? 1 : (p == 5) ? 2 : (p == 7) ? 3 : (p == 8) ? 4 : 5;
        int xm = 1 << lb;
        bool up = (lane >> lb) & 1;
#pragma unroll
        for (int r = 0; r < 8; ++r) {
          float wx = __shfl_xor(a[r].x, xm, 64);
          float wy = __shfl_xor(a[r].y, xm, 64);
          float n2 = a[r].x * a[r].x + a[r].y * a[r].y;
          if (!up) {
            cr += a[r].x * wx + a[r].y * wy;
            ci += a[r].x * wy - a[r].y * wx;
            zz += n2;
          } else {
            zz -= n2;
          }
        }
      }
      obs[i] = 2.f * cr;
      obs[10 + i] = 2.f * ci;
      obs[20 + i] = zz;
    }
#pragma unroll
    for (int j = 0; j < 30; ++j) obs[j] = wave_sum(obs[j]);

    float* Rf = (float*)R2;
    __syncthreads();                 // R2 free (mix-2 gather long done)
    if (lane == 0) {
#pragma unroll
      for (int j = 0; j < 30; ++j) Rf[w * 30 + j] = obs[j];
    }
    __syncthreads();
    if (w == 0) {
      if (lane < 30) {
        float v = Rf[0 * 30 + lane] + Rf[1 * 30 + lane] +
                  Rf[2 * 30 + lane] + Rf[3 * 30 + lane];
        atomicAdd(&sv[b * 30 + lane], v);
      }
      // last-arriving block of group b computes the output row
      int lastflag = 0;
      if (lane == 0) {
        unsigned old = __hip_atomic_fetch_add(&g_gb[b].done, 1u, __ATOMIC_ACQ_REL,
                                              __HIP_MEMORY_SCOPE_AGENT);
        lastflag = ((old & 7u) == 7u) ? 1 : 0;
      }
      lastflag = __shfl(lastflag, 0, 64);
      if (lastflag) {
        (void)__hip_atomic_load(&g_gb[b].done, __ATOMIC_ACQUIRE, __HIP_MEMORY_SCOPE_AGENT);
        if (lane < 8) {
          float acc = b_out[lane];
#pragma unroll
          for (int j = 0; j < 30; ++j) acc += W_out[lane * 30 + j] * sv[b * 30 + j];
          out[b * 8 + lane] = acc;
        }
      }
    }
  }
}

extern "C" void kernel_launch(void* const* d_in, const int* in_sizes, int n_in,
                              void* d_out, int out_size, void* d_ws, size_t ws_size,
                              hipStream_t stream) {
  const float* x     = (const float*)d_in[0];
  const float* W_fp  = (const float*)d_in[1];
  const float* b_fp  = (const float*)d_in[2];
  const float* prep  = (const float*)d_in[3];
  const float* sig   = (const float*)d_in[4];
  const float* qff   = (const float*)d_in[5];
  const float* W_out = (const float*)d_in[6];
  const float* b_out = (const float*)d_in[7];
  float* out = (float*)d_out;
  (void)in_sizes; (void)n_in; (void)out_size;

  // ws: part1 (1 MB) | part2 (1 MB) | sv (1920 B). Needs ~2.1 MB.
  char* ws = (char*)d_ws;
  const size_t SZ_PART = (size_t)128 * 512 * 16;   // 128 block-partials * 8 KB
  float4* part1 = (float4*)ws;
  float4* part2 = (float4*)(ws + SZ_PART);
  float*  sv    = (float*)(ws + 2 * SZ_PART);
  (void)ws_size;

  k_fused<<<dim3(128), dim3(256), 0, stream>>>(x, W_fp, b_fp, prep, sig, qff,
                                               W_out, b_out, out, part1, part2, sv);
}